// Round 4
// baseline (79.060 us; speedup 1.0000x reference)
//
#include <hip/hip_runtime.h>
#include <math.h>

#define BB 16
#define TT 128
#define MM 32
#define PP 64
#define CC 256

// ---- K1: per (b,m), 512 threads: w_in, eff_c, eff_p, nrm, MLP -> out_p ----
__global__ __launch_bounds__(512) void K1_front(
        const float* __restrict__ pointers,
        const float* __restrict__ contents,
        const float* __restrict__ receivers,
        const float* __restrict__ W1,
        const float* __restrict__ b1,
        const float* __restrict__ W2,
        const float* __restrict__ b2,
        float* __restrict__ eff_c_ws,
        float* __restrict__ nrm_ws,
        float* __restrict__ outp_g) {
    const int bm = blockIdx.x;
    const int b = bm >> 5, m = bm & 31;
    const int tid = threadIdx.x;
    const int lane = tid & 63, w = tid >> 6;

    __shared__ float w_in[TT];
    __shared__ float ri[PP + CC];       // [eff_p | eff_c]
    __shared__ float partc[2][CC];
    __shared__ float part8[8][PP];
    __shared__ float h[PP];
    __shared__ float red[4];

    // w_in: 4 lanes per token, contiguous float4 reads
    {
        const int t = tid >> 2, q = tid & 3;
        const float4* pr4 = reinterpret_cast<const float4*>(pointers + (b * TT + t) * PP + q * 16);
        const float4* rc4 = reinterpret_cast<const float4*>(receivers + m * PP + q * 16);
        float s = 0.f;
        #pragma unroll
        for (int k = 0; k < 4; ++k) {
            float4 v = pr4[k], rv = rc4[k];
            s += v.x * rv.x + v.y * rv.y + v.z * rv.z + v.w * rv.w;
        }
        s += __shfl_xor(s, 1, 64);
        s += __shfl_xor(s, 2, 64);
        if (q == 0) { float th = tanhf(s); w_in[t] = th > 0.f ? th : 0.f; }
    }
    __syncthreads();
    // eff_c partials: c = tid&255, 2 t-groups of 64
    {
        const int c = tid & 255, g = tid >> 8;
        const float* cb = contents + (b * TT + g * 64) * CC + c;
        float acc = 0.f;
        #pragma unroll 4
        for (int t = 0; t < 64; ++t) acc += w_in[g * 64 + t] * cb[t * CC];
        partc[g][c] = acc;
    }
    // eff_p partials: p = tid&63, 8 t-groups of 16
    {
        const int p = tid & 63, g = tid >> 6;
        const float* pb = pointers + (b * TT + g * 16) * PP + p;
        float acc = 0.f;
        #pragma unroll
        for (int t = 0; t < 16; ++t) acc += w_in[g * 16 + t] * pb[t * PP];
        part8[g][p] = acc;
    }
    __syncthreads();
    float ecv = 0.f;
    if (tid < CC) {
        ecv = partc[0][tid] + partc[1][tid];
        ri[PP + tid] = ecv;
        eff_c_ws[bm * CC + tid] = ecv;
        float v = ecv * ecv;
        #pragma unroll
        for (int off = 32; off; off >>= 1) v += __shfl_xor(v, off, 64);
        if (lane == 0) red[w] = v;
    } else if (tid < CC + PP) {
        const int p = tid - CC;
        float a = 0.f;
        #pragma unroll
        for (int g = 0; g < 8; ++g) a += part8[g][p];
        ri[p] = a;
    }
    __syncthreads();
    if (tid < CC) {
        const float ss = red[0] + red[1] + red[2] + red[3];
        nrm_ws[bm * CC + tid] = ecv / (ss + 1e-42f);
    }
    // MLP layer 1: o = lane, 8 i-segments of 40
    {
        const float* w1 = W1 + m * 320 * 64;
        float acc = 0.f;
        const int i0 = w * 40;
        #pragma unroll 8
        for (int i = i0; i < i0 + 40; ++i) acc += ri[i] * w1[i * 64 + lane];
        part8[w][lane] = acc;
    }
    __syncthreads();
    if (tid < PP) {
        float s = b1[m * PP + tid];
        #pragma unroll
        for (int g = 0; g < 8; ++g) s += part8[g][tid];
        h[tid] = s > 0.f ? s : 0.f;
    }
    __syncthreads();
    // MLP layer 2
    {
        const float* w2 = W2 + m * 64 * 64;
        float acc = 0.f;
        const int i0 = w * 8;
        #pragma unroll
        for (int i = i0; i < i0 + 8; ++i) acc += h[i] * w2[i * 64 + lane];
        part8[w][lane] = acc;
    }
    __syncthreads();
    if (tid < PP) {
        float s = b2[m * PP + tid];
        #pragma unroll
        for (int g = 0; g < 8; ++g) s += part8[g][tid];
        outp_g[bm * PP + tid] = s > 0.f ? s : 0.f;
    }
}

// ---- K2: per (m, cg): out_c rows cg*32..+31 for ALL 16 batches ------------
// mem rows read ONCE into registers; cg==0 blocks also compute w_out[:,m,:]
__global__ __launch_bounds__(256) void K2_outc(
        const float* __restrict__ memories,
        const float* __restrict__ eff_c_ws,
        const float* __restrict__ outp_g,
        float* __restrict__ outc_g,
        float* __restrict__ wout_ws) {
    const int m = blockIdx.x >> 3, cg = blockIdx.x & 7;
    const int tid = threadIdx.x;
    const int lane = tid & 63, w = tid >> 6;
    __shared__ float e_lds[16][CC];
    __shared__ float outc_s[16][32];

    for (int b = 0; b < 16; ++b)
        e_lds[b][tid] = eff_c_ws[(b * MM + m) * CC + tid];

    if (cg == 0) {
        // w_out[b,m,n] = relu(tanh(out_p[b,m,:].out_p[b,n,:])); 2 dots/thread
        #pragma unroll
        for (int k = 0; k < 2; ++k) {
            const int idx = k * 256 + tid;
            const int b = idx >> 5, n = idx & 31;
            const float4* pm = reinterpret_cast<const float4*>(outp_g + (b * MM + m) * PP);
            const float4* pn = reinterpret_cast<const float4*>(outp_g + (b * MM + n) * PP);
            float s = 0.f;
            #pragma unroll
            for (int i = 0; i < 16; ++i) {
                float4 a = pm[i], c = pn[i];
                s += a.x * c.x + a.y * c.y + a.z * c.z + a.w * c.w;
            }
            float th = tanhf(s);
            wout_ws[(m * 16 + b) * 32 + n] = th > 0.f ? th : 0.f;
        }
    }
    __syncthreads();

    // matvec: 8 lanes per row; lane owns 32-float d-chunk in registers
    const int rsub = lane >> 3, j = lane & 7;
    const int c_local = w * 8 + rsub;
    const int c = cg * 32 + c_local;
    float4 mr[8];
    const float4* mrow = reinterpret_cast<const float4*>(memories + (m * CC + c) * CC + j * 32);
    #pragma unroll
    for (int k = 0; k < 8; ++k) mr[k] = mrow[k];

    for (int b = 0; b < 16; ++b) {
        const float4* e4 = reinterpret_cast<const float4*>(&e_lds[b][0]);
        float acc = 0.f;
        #pragma unroll
        for (int k = 0; k < 8; ++k) {
            const int kk = (k + j) & 7;           // bank-swizzled order
            float4 ev = e4[j * 8 + kk];
            acc += mr[kk].x * ev.x + mr[kk].y * ev.y + mr[kk].z * ev.z + mr[kk].w * ev.w;
        }
        acc += __shfl_xor(acc, 1, 64);
        acc += __shfl_xor(acc, 2, 64);
        acc += __shfl_xor(acc, 4, 64);
        if (j == 0) outc_s[b][c_local] = acc;
    }
    __syncthreads();
    #pragma unroll
    for (int k = 0; k < 2; ++k) {
        const int idx = k * 256 + tid;
        const int b = idx >> 5, cl = idx & 31;
        outc_g[(b * MM + m) * CC + cg * 32 + cl] = outc_s[b][cl];
    }
}

// ---- K3: per (m, cq): 16-row mem tile in regs, stream all 16 batches ------
__global__ __launch_bounds__(1024) void K3_stream(
        const float* __restrict__ memories,
        const float* __restrict__ outc_g,
        const float* __restrict__ wout_ws,
        const float* __restrict__ nrm_ws,
        float* __restrict__ mems_out) {
    const int m = blockIdx.x >> 4, cq = blockIdx.x & 15;
    const int tid = threadIdx.x;
    const int c_local = tid >> 6, d4 = tid & 63;

    __shared__ float nrm_lds[16][CC];      // 16 KB
    __shared__ float wout_lds[16][32];     // 2 KB
    __shared__ float eoc_s[16][16];        // 1 KB

    // mem tile: one float4 per thread, read once
    const float4 mv = reinterpret_cast<const float4*>(memories)[(m * CC + cq * 16 + c_local) * 64 + d4];

    #pragma unroll
    for (int k = 0; k < 4; ++k) {
        const int idx = k * 1024 + tid;
        const int b = idx >> 8, d = idx & 255;
        nrm_lds[b][d] = nrm_ws[(b * MM + m) * CC + d];
    }
    if (tid < 512) wout_lds[tid >> 5][tid & 31] = wout_ws[m * 512 + tid];
    __syncthreads();

    // eoc[b, cl] = sum_n wout[b,n] * out_c[b,n,c]; 4 lanes per (b,cl)
    {
        const int pair = tid >> 2, k = tid & 3;
        const int b = pair >> 4, cl = pair & 15;
        const int c = cq * 16 + cl;
        float s = 0.f;
        #pragma unroll
        for (int n8 = 0; n8 < 8; ++n8) {
            const int n = k * 8 + n8;
            s += wout_lds[b][n] * outc_g[(b * MM + n) * CC + c];
        }
        s += __shfl_xor(s, 1, 64);
        s += __shfl_xor(s, 2, 64);
        if (k == 0) eoc_s[b][cl] = s;
    }
    __syncthreads();

    float4* out4 = reinterpret_cast<float4*>(mems_out);
    #pragma unroll 4
    for (int b = 0; b < 16; ++b) {
        const float e = eoc_s[b][c_local];
        const float4 nv = reinterpret_cast<const float4*>(&nrm_lds[b][0])[d4];
        float4 o;
        o.x = 0.5f * (mv.x + e * nv.x);
        o.y = 0.5f * (mv.y + e * nv.y);
        o.z = 0.5f * (mv.z + e * nv.z);
        o.w = 0.5f * (mv.w + e * nv.w);
        out4[((b * MM + m) * CC + cq * 16 + c_local) * 64 + d4] = o;
    }
}

extern "C" void kernel_launch(void* const* d_in, const int* in_sizes, int n_in,
                              void* d_out, int out_size, void* d_ws, size_t ws_size,
                              hipStream_t stream) {
    const float* pointers  = (const float*)d_in[0];
    const float* contents  = (const float*)d_in[1];
    const float* receivers = (const float*)d_in[2];
    const float* memories  = (const float*)d_in[3];
    const float* W1 = (const float*)d_in[4];
    const float* b1 = (const float*)d_in[5];
    const float* W2 = (const float*)d_in[6];
    const float* b2 = (const float*)d_in[7];

    float* out      = (float*)d_out;
    float* outp_g   = out;                       // 16*32*64
    float* outc_g   = out + 32768;               // 16*32*256
    float* mems_out = out + 32768 + 131072;      // 16*32*256*256

    float* ws    = (float*)d_ws;
    float* eff_c = ws;                 // 131072
    float* nrm   = ws + 131072;        // 131072
    float* wout  = ws + 262144;        // 16384

    hipLaunchKernelGGL(K1_front, dim3(BB * MM), dim3(512), 0, stream,
                       pointers, contents, receivers, W1, b1, W2, b2,
                       eff_c, nrm, outp_g);
    hipLaunchKernelGGL(K2_outc, dim3(MM * 8), dim3(256), 0, stream,
                       memories, eff_c, outp_g, outc_g, wout);
    hipLaunchKernelGGL(K3_stream, dim3(MM * 16), dim3(1024), 0, stream,
                       memories, outc_g, wout, nrm, mems_out);
}

// Round 6
// 57.916 us; speedup vs baseline: 1.3651x; 1.3651x over previous
//
#include <hip/hip_runtime.h>
#include <math.h>

#define BB 16
#define TT 128
#define MM 32
#define PP 64
#define CC 256

typedef float f32x4 __attribute__((ext_vector_type(4)));

// ---- K1: per (b,m): w_in -> eff_c, eff_p; out_c = mem[m]@eff_c; MLP -> out_p
// 512 threads (8 waves)
__global__ __launch_bounds__(512) void K1_front(
        const float* __restrict__ pointers,
        const float* __restrict__ contents,
        const float* __restrict__ receivers,
        const float* __restrict__ memories,
        const float* __restrict__ W1,
        const float* __restrict__ b1,
        const float* __restrict__ W2,
        const float* __restrict__ b2,
        float* __restrict__ eff_c_ws,
        float* __restrict__ outp_g,
        float* __restrict__ outc_g) {
    const int bm = blockIdx.x;
    const int b = bm >> 5, m = bm & 31;
    const int tid = threadIdx.x;
    const int lane = tid & 63, w = tid >> 6;

    __shared__ float w_in[TT];
    __shared__ float ri[PP + CC];      // [eff_p | eff_c]
    __shared__ float partc[2][CC];
    __shared__ float part8[8][PP];
    __shared__ float h[PP];
    __shared__ float outc_s[CC];

    // ---- w_in: 4 lanes per token, contiguous float4 reads ----
    {
        const int t = tid >> 2, q = tid & 3;
        const float4* pr4 = reinterpret_cast<const float4*>(pointers + (b * TT + t) * PP + q * 16);
        const float4* rc4 = reinterpret_cast<const float4*>(receivers + m * PP + q * 16);
        float s = 0.f;
        #pragma unroll
        for (int k = 0; k < 4; ++k) {
            float4 v = pr4[k], rv = rc4[k];
            s += v.x * rv.x + v.y * rv.y + v.z * rv.z + v.w * rv.w;
        }
        s += __shfl_xor(s, 1, 64);
        s += __shfl_xor(s, 2, 64);
        if (q == 0) {
            float th = tanhf(s);
            w_in[t] = th > 0.f ? th : 0.f;
        }
    }
    __syncthreads();
    // ---- eff_c partials: c = tid&255, 2 t-groups of 64 ----
    {
        const int c = tid & 255, g = tid >> 8;
        const float* cb = contents + (b * TT + g * 64) * CC + c;
        float acc = 0.f;
        #pragma unroll 4
        for (int t = 0; t < 64; ++t) acc += w_in[g * 64 + t] * cb[t * CC];
        partc[g][c] = acc;
    }
    // ---- eff_p partials: p = tid&63, 8 t-groups of 16 ----
    {
        const int p = tid & 63, g = tid >> 6;
        const float* pb = pointers + (b * TT + g * 16) * PP + p;
        float acc = 0.f;
        #pragma unroll
        for (int t = 0; t < 16; ++t) acc += w_in[g * 16 + t] * pb[t * PP];
        part8[g][p] = acc;
    }
    __syncthreads();
    if (tid < CC) {
        float e = partc[0][tid] + partc[1][tid];
        ri[PP + tid] = e;
        eff_c_ws[bm * CC + tid] = e;
    } else if (tid < CC + PP) {
        const int p = tid - CC;
        float a = 0.f;
        #pragma unroll
        for (int g = 0; g < 8; ++g) a += part8[g][p];
        ri[p] = a;
    }
    __syncthreads();

    // ---- out_c = mem[m] @ eff_c: wave w rows w*32..w*32+31, float4 + shfl ----
    {
        const float e0 = ri[PP + lane * 4 + 0], e1 = ri[PP + lane * 4 + 1];
        const float e2 = ri[PP + lane * 4 + 2], e3 = ri[PP + lane * 4 + 3];
        const float4* mem4 = reinterpret_cast<const float4*>(memories) + m * (CC * CC / 4);
        for (int r = 0; r < 32; ++r) {
            const int c = w * 32 + r;
            float4 mv = mem4[c * 64 + lane];
            float pp = mv.x * e0 + mv.y * e1 + mv.z * e2 + mv.w * e3;
            #pragma unroll
            for (int off = 32; off; off >>= 1) pp += __shfl_xor(pp, off, 64);
            if (lane == 0) outc_s[c] = pp;
        }
    }

    // ---- MLP: h = relu(ri @ W1 + b1) ----
    {
        const float* w1 = W1 + m * 320 * 64;
        float acc = 0.f;
        const int i0 = w * 40;
        #pragma unroll 8
        for (int i = i0; i < i0 + 40; ++i) acc += ri[i] * w1[i * 64 + lane];
        __syncthreads();               // also covers outc_s completion
        part8[w][lane] = acc;
    }
    __syncthreads();
    if (tid < PP) {
        float s = b1[m * PP + tid];
        #pragma unroll
        for (int g = 0; g < 8; ++g) s += part8[g][tid];
        h[tid] = s > 0.f ? s : 0.f;
    }
    __syncthreads();
    {
        const float* w2 = W2 + m * 64 * 64;
        float acc = 0.f;
        const int i0 = w * 8;
        #pragma unroll
        for (int i = i0; i < i0 + 8; ++i) acc += h[i] * w2[i * 64 + lane];
        part8[w][lane] = acc;
    }
    __syncthreads();
    if (tid < PP) {
        float s = b2[m * PP + tid];
        #pragma unroll
        for (int g = 0; g < 8; ++g) s += part8[g][tid];
        outp_g[bm * PP + tid] = s > 0.f ? s : 0.f;
    }
    if (tid < CC) outc_g[bm * CC + tid] = outc_s[tid];
}

// ---- K2: per (b,m): w_out, eoc, nrm -> ws (256 threads) -------------------
__global__ __launch_bounds__(256) void K2_route(
        const float* __restrict__ outp_g,
        const float* __restrict__ outc_g,
        const float* __restrict__ eff_c_ws,
        float* __restrict__ eoc_ws,
        float* __restrict__ nrm_ws) {
    const int bm = blockIdx.x;
    const int b = bm >> 5;
    const int tid = threadIdx.x;
    __shared__ float op[PP];
    __shared__ float wout[MM];
    __shared__ float red[4];
    if (tid < PP) op[tid] = outp_g[bm * PP + tid];
    __syncthreads();
    // w_out[n]: 8 lanes per n
    {
        const int n = tid >> 3, j = tid & 7;
        const float* opn = outp_g + (b * MM + n) * PP + j * 8;
        float s = 0.f;
        #pragma unroll
        for (int k = 0; k < 8; ++k) s += op[j * 8 + k] * opn[k];
        s += __shfl_xor(s, 1, 64);
        s += __shfl_xor(s, 2, 64);
        s += __shfl_xor(s, 4, 64);
        if (j == 0) {
            float th = tanhf(s);
            wout[n] = th > 0.f ? th : 0.f;
        }
    }
    __syncthreads();
    // eoc[c] = sum_n wout[n]*out_c[b,n,c]
    {
        float acc = 0.f;
        const float* cb = outc_g + b * MM * CC + tid;
        #pragma unroll 4
        for (int n = 0; n < MM; ++n) acc += wout[n] * cb[n * CC];
        eoc_ws[bm * CC + tid] = acc;
    }
    // nrm = eff_c / (||eff_c||^2 + eps)
    {
        float ec = eff_c_ws[bm * CC + tid];
        float v = ec * ec;
        #pragma unroll
        for (int off = 32; off; off >>= 1) v += __shfl_xor(v, off, 64);
        if ((tid & 63) == 0) red[tid >> 6] = v;
        __syncthreads();
        const float ss = red[0] + red[1] + red[2] + red[3];
        nrm_ws[bm * CC + tid] = ec / (ss + 1e-42f);
    }
}

// ---- K3: pure stream: out = 0.5*(mem + eoc (x) nrm) -----------------------
// grid = 8192, b-MAJOR: gid = b*512 + m*16 + cq  -> all 16 b-blocks of a
// (m,cq) tile land on the same XCD (512 % 8 == 0): tile read once, 15 L2 hits.
__global__ __launch_bounds__(256) void K3_stream(
        const float* __restrict__ memories,
        const float* __restrict__ eoc_ws,
        const float* __restrict__ nrm_ws,
        float* __restrict__ mems_out) {
    const int gid = blockIdx.x;
    const int b = gid >> 9;
    const int mcq = gid & 511;
    const int m = mcq >> 4, cq = mcq & 15;
    const int bm = b * MM + m;
    const int tid = threadIdx.x;
    const int lane = tid & 63, w = tid >> 6;

    // independent small loads first
    const float4 nv = reinterpret_cast<const float4*>(nrm_ws)[bm * 64 + lane];
    const float* eoc = eoc_ws + bm * CC + cq * 16;
    float e[4];
    #pragma unroll
    for (int k = 0; k < 4; ++k) e[k] = eoc[k * 4 + w];

    const f32x4* mem4 = reinterpret_cast<const f32x4*>(memories) + (m * 16 + cq) * 1024;
    f32x4* out4 = reinterpret_cast<f32x4*>(mems_out) + bm * (CC * CC / 4) + cq * 1024;

    #pragma unroll
    for (int k = 0; k < 4; ++k) {
        const int idx = k * 256 + tid;
        f32x4 mv = mem4[idx];
        f32x4 o;
        o.x = 0.5f * (mv.x + e[k] * nv.x);
        o.y = 0.5f * (mv.y + e[k] * nv.y);
        o.z = 0.5f * (mv.z + e[k] * nv.z);
        o.w = 0.5f * (mv.w + e[k] * nv.w);
        __builtin_nontemporal_store(o, &out4[idx]);
    }
}

extern "C" void kernel_launch(void* const* d_in, const int* in_sizes, int n_in,
                              void* d_out, int out_size, void* d_ws, size_t ws_size,
                              hipStream_t stream) {
    const float* pointers  = (const float*)d_in[0];
    const float* contents  = (const float*)d_in[1];
    const float* receivers = (const float*)d_in[2];
    const float* memories  = (const float*)d_in[3];
    const float* W1 = (const float*)d_in[4];
    const float* b1 = (const float*)d_in[5];
    const float* W2 = (const float*)d_in[6];
    const float* b2 = (const float*)d_in[7];

    float* out      = (float*)d_out;
    float* outp_g   = out;                       // 16*32*64
    float* outc_g   = out + 32768;               // 16*32*256
    float* mems_out = out + 32768 + 131072;      // 16*32*256*256

    float* ws    = (float*)d_ws;
    float* eff_c = ws;                 // 131072
    float* eoc   = ws + 131072;        // 131072
    float* nrm   = ws + 262144;        // 131072

    hipLaunchKernelGGL(K1_front, dim3(BB * MM), dim3(512), 0, stream,
                       pointers, contents, receivers, memories, W1, b1, W2, b2,
                       eff_c, outp_g, outc_g);
    hipLaunchKernelGGL(K2_route, dim3(BB * MM), dim3(256), 0, stream,
                       outp_g, outc_g, eff_c, eoc, nrm);
    hipLaunchKernelGGL(K3_stream, dim3(BB * MM * 16), dim3(256), 0, stream,
                       memories, eoc, nrm, mems_out);
}

// Round 7
// 56.616 us; speedup vs baseline: 1.3964x; 1.0229x over previous
//
#include <hip/hip_runtime.h>
#include <math.h>

#define BB 16
#define TT 128
#define MM 32
#define PP 64
#define CC 256

typedef float f32x4 __attribute__((ext_vector_type(4)));

// ---- K1: per (b,m): w_in -> eff_c, eff_p; out_c = mem[m]@eff_c; MLP -> out_p
// 512 threads (8 waves)
__global__ __launch_bounds__(512) void K1_front(
        const float* __restrict__ pointers,
        const float* __restrict__ contents,
        const float* __restrict__ receivers,
        const float* __restrict__ memories,
        const float* __restrict__ W1,
        const float* __restrict__ b1,
        const float* __restrict__ W2,
        const float* __restrict__ b2,
        float* __restrict__ eff_c_ws,
        float* __restrict__ outp_g,
        float* __restrict__ outc_g) {
    const int bm = blockIdx.x;
    const int b = bm >> 5, m = bm & 31;
    const int tid = threadIdx.x;
    const int lane = tid & 63, w = tid >> 6;

    __shared__ float w_in[TT];
    __shared__ float ri[PP + CC];      // [eff_p | eff_c]
    __shared__ float partc[2][CC];
    __shared__ float part8[8][PP];
    __shared__ float h[PP];
    __shared__ float outc_s[CC];

    // ---- w_in: 4 lanes per token, contiguous float4 reads ----
    {
        const int t = tid >> 2, q = tid & 3;
        const float4* pr4 = reinterpret_cast<const float4*>(pointers + (b * TT + t) * PP + q * 16);
        const float4* rc4 = reinterpret_cast<const float4*>(receivers + m * PP + q * 16);
        float s = 0.f;
        #pragma unroll
        for (int k = 0; k < 4; ++k) {
            float4 v = pr4[k], rv = rc4[k];
            s += v.x * rv.x + v.y * rv.y + v.z * rv.z + v.w * rv.w;
        }
        s += __shfl_xor(s, 1, 64);
        s += __shfl_xor(s, 2, 64);
        if (q == 0) {
            float th = tanhf(s);
            w_in[t] = th > 0.f ? th : 0.f;
        }
    }
    __syncthreads();
    // ---- eff_c partials: c = tid&255, 2 t-groups of 64 ----
    {
        const int c = tid & 255, g = tid >> 8;
        const float* cb = contents + (b * TT + g * 64) * CC + c;
        float acc = 0.f;
        #pragma unroll 4
        for (int t = 0; t < 64; ++t) acc += w_in[g * 64 + t] * cb[t * CC];
        partc[g][c] = acc;
    }
    // ---- eff_p partials: p = tid&63, 8 t-groups of 16 ----
    {
        const int p = tid & 63, g = tid >> 6;
        const float* pb = pointers + (b * TT + g * 16) * PP + p;
        float acc = 0.f;
        #pragma unroll
        for (int t = 0; t < 16; ++t) acc += w_in[g * 16 + t] * pb[t * PP];
        part8[g][p] = acc;
    }
    __syncthreads();
    if (tid < CC) {
        float e = partc[0][tid] + partc[1][tid];
        ri[PP + tid] = e;
        eff_c_ws[bm * CC + tid] = e;
    } else if (tid < CC + PP) {
        const int p = tid - CC;
        float a = 0.f;
        #pragma unroll
        for (int g = 0; g < 8; ++g) a += part8[g][p];
        ri[p] = a;
    }
    __syncthreads();

    // ---- out_c = mem[m] @ eff_c: wave w rows w*32..w*32+31, float4 + shfl ----
    {
        const float e0 = ri[PP + lane * 4 + 0], e1 = ri[PP + lane * 4 + 1];
        const float e2 = ri[PP + lane * 4 + 2], e3 = ri[PP + lane * 4 + 3];
        const float4* mem4 = reinterpret_cast<const float4*>(memories) + m * (CC * CC / 4);
        for (int r = 0; r < 32; ++r) {
            const int c = w * 32 + r;
            float4 mv = mem4[c * 64 + lane];
            float pp = mv.x * e0 + mv.y * e1 + mv.z * e2 + mv.w * e3;
            #pragma unroll
            for (int off = 32; off; off >>= 1) pp += __shfl_xor(pp, off, 64);
            if (lane == 0) outc_s[c] = pp;
        }
    }

    // ---- MLP: h = relu(ri @ W1 + b1) ----
    {
        const float* w1 = W1 + m * 320 * 64;
        float acc = 0.f;
        const int i0 = w * 40;
        #pragma unroll 8
        for (int i = i0; i < i0 + 40; ++i) acc += ri[i] * w1[i * 64 + lane];
        __syncthreads();               // also covers outc_s completion
        part8[w][lane] = acc;
    }
    __syncthreads();
    if (tid < PP) {
        float s = b1[m * PP + tid];
        #pragma unroll
        for (int g = 0; g < 8; ++g) s += part8[g][tid];
        h[tid] = s > 0.f ? s : 0.f;
    }
    __syncthreads();
    {
        const float* w2 = W2 + m * 64 * 64;
        float acc = 0.f;
        const int i0 = w * 8;
        #pragma unroll
        for (int i = i0; i < i0 + 8; ++i) acc += h[i] * w2[i * 64 + lane];
        part8[w][lane] = acc;
    }
    __syncthreads();
    if (tid < PP) {
        float s = b2[m * PP + tid];
        #pragma unroll
        for (int g = 0; g < 8; ++g) s += part8[g][tid];
        outp_g[bm * PP + tid] = s > 0.f ? s : 0.f;
    }
    if (tid < CC) outc_g[bm * CC + tid] = outc_s[tid];
}

// ---- K3': fused route+stream. grid = 8192, b-MAJOR: gid = b*512 + m*16 + cq
// Prologue per block: nrm (256-dot), w_out row (32x 64-dot), eoc slice
// (16x 32-dot). Then NT-stream 16 KB tile. Same-XCD tile reuse (512 % 8 == 0).
__global__ __launch_bounds__(256) void K3_fused(
        const float* __restrict__ memories,
        const float* __restrict__ outp_g,
        const float* __restrict__ outc_g,
        const float* __restrict__ eff_c_ws,
        float* __restrict__ mems_out) {
    const int gid = blockIdx.x;
    const int b = gid >> 9;
    const int mcq = gid & 511;
    const int m = mcq >> 4, cq = mcq & 15;
    const int bm = b * MM + m;
    const int tid = threadIdx.x;
    const int lane = tid & 63, w = tid >> 6;

    __shared__ float wout_s[MM];
    __shared__ float nrm_s[CC];
    __shared__ float eoc_s[16];
    __shared__ float red[4];

    // ---- nrm partial: ||eff_c||^2 ----
    const float ec = eff_c_ws[bm * CC + tid];
    {
        float v = ec * ec;
        #pragma unroll
        for (int off = 32; off; off >>= 1) v += __shfl_xor(v, off, 64);
        if (lane == 0) red[w] = v;
    }
    // ---- w_out row m: n = tid>>3, j = tid&7 (8 lanes per n) ----
    {
        const int n = tid >> 3, j = tid & 7;
        const float* opm = outp_g + bm * PP + j * 8;
        const float* opn = outp_g + (b * MM + n) * PP + j * 8;
        float s = 0.f;
        #pragma unroll
        for (int k = 0; k < 8; ++k) s += opm[k] * opn[k];
        s += __shfl_xor(s, 1, 64);
        s += __shfl_xor(s, 2, 64);
        s += __shfl_xor(s, 4, 64);
        if (j == 0) {
            float th = tanhf(s);
            wout_s[n] = th > 0.f ? th : 0.f;
        }
    }
    __syncthreads();
    nrm_s[tid] = ec / (red[0] + red[1] + red[2] + red[3] + 1e-42f);
    // ---- eoc slice: c_local = tid>>4, k = tid&15, 2 n's per lane ----
    {
        const int c_local = tid >> 4, k = tid & 15;
        const int c = cq * 16 + c_local;
        const float* cb = outc_g + b * MM * CC + c;
        float s = wout_s[2 * k] * cb[(2 * k) * CC]
                + wout_s[2 * k + 1] * cb[(2 * k + 1) * CC];
        s += __shfl_xor(s, 1, 64);
        s += __shfl_xor(s, 2, 64);
        s += __shfl_xor(s, 4, 64);
        s += __shfl_xor(s, 8, 64);
        if (k == 0) eoc_s[c_local] = s;
    }
    __syncthreads();

    // ---- stream 16 rows x 256 cols, NT stores ----
    const float4 nv = reinterpret_cast<const float4*>(nrm_s)[lane];
    float e[4];
    #pragma unroll
    for (int k = 0; k < 4; ++k) e[k] = eoc_s[k * 4 + w];

    const f32x4* mem4 = reinterpret_cast<const f32x4*>(memories) + (m * 16 + cq) * 1024;
    f32x4* out4 = reinterpret_cast<f32x4*>(mems_out) + bm * (CC * CC / 4) + cq * 1024;

    #pragma unroll
    for (int k = 0; k < 4; ++k) {
        const int idx = k * 256 + tid;
        f32x4 mv = mem4[idx];
        f32x4 o;
        o.x = 0.5f * (mv.x + e[k] * nv.x);
        o.y = 0.5f * (mv.y + e[k] * nv.y);
        o.z = 0.5f * (mv.z + e[k] * nv.z);
        o.w = 0.5f * (mv.w + e[k] * nv.w);
        __builtin_nontemporal_store(o, &out4[idx]);
    }
}

extern "C" void kernel_launch(void* const* d_in, const int* in_sizes, int n_in,
                              void* d_out, int out_size, void* d_ws, size_t ws_size,
                              hipStream_t stream) {
    const float* pointers  = (const float*)d_in[0];
    const float* contents  = (const float*)d_in[1];
    const float* receivers = (const float*)d_in[2];
    const float* memories  = (const float*)d_in[3];
    const float* W1 = (const float*)d_in[4];
    const float* b1 = (const float*)d_in[5];
    const float* W2 = (const float*)d_in[6];
    const float* b2 = (const float*)d_in[7];

    float* out      = (float*)d_out;
    float* outp_g   = out;                       // 16*32*64
    float* outc_g   = out + 32768;               // 16*32*256
    float* mems_out = out + 32768 + 131072;      // 16*32*256*256

    float* eff_c = (float*)d_ws;       // 131072 floats

    hipLaunchKernelGGL(K1_front, dim3(BB * MM), dim3(512), 0, stream,
                       pointers, contents, receivers, memories, W1, b1, W2, b2,
                       eff_c, outp_g, outc_g);
    hipLaunchKernelGGL(K3_fused, dim3(BB * MM * 16), dim3(256), 0, stream,
                       memories, outp_g, outc_g, eff_c, mems_out);
}

// Round 8
// 46.798 us; speedup vs baseline: 1.6894x; 1.2098x over previous
//
#include <hip/hip_runtime.h>
#include <math.h>

#define BB 16
#define TT 128
#define MM 32
#define PP 64
#define CC 256

typedef float f32x4 __attribute__((ext_vector_type(4)));

// ---- K1: per (b,m): w_in -> eff_c, eff_p; out_c = mem[m]@eff_c; MLP -> out_p
// 512 threads (8 waves)
__global__ __launch_bounds__(512) void K1_front(
        const float* __restrict__ pointers,
        const float* __restrict__ contents,
        const float* __restrict__ receivers,
        const float* __restrict__ memories,
        const float* __restrict__ W1,
        const float* __restrict__ b1,
        const float* __restrict__ W2,
        const float* __restrict__ b2,
        float* __restrict__ eff_c_ws,
        float* __restrict__ outp_g,
        float* __restrict__ outc_g) {
    const int bm = blockIdx.x;
    const int b = bm >> 5, m = bm & 31;
    const int tid = threadIdx.x;
    const int lane = tid & 63, w = tid >> 6;

    __shared__ float w_in[TT];
    __shared__ float ri[PP + CC];      // [eff_p | eff_c]
    __shared__ float partc[2][CC];
    __shared__ float part8[8][PP];
    __shared__ float h[PP];
    __shared__ float outc_s[CC];

    // ---- w_in: 4 lanes per token, contiguous float4 reads ----
    {
        const int t = tid >> 2, q = tid & 3;
        const float4* pr4 = reinterpret_cast<const float4*>(pointers + (b * TT + t) * PP + q * 16);
        const float4* rc4 = reinterpret_cast<const float4*>(receivers + m * PP + q * 16);
        float s = 0.f;
        #pragma unroll
        for (int k = 0; k < 4; ++k) {
            float4 v = pr4[k], rv = rc4[k];
            s += v.x * rv.x + v.y * rv.y + v.z * rv.z + v.w * rv.w;
        }
        s += __shfl_xor(s, 1, 64);
        s += __shfl_xor(s, 2, 64);
        if (q == 0) {
            float th = tanhf(s);
            w_in[t] = th > 0.f ? th : 0.f;
        }
    }
    __syncthreads();
    // ---- eff_c partials: c = tid&255, 2 t-groups of 64 ----
    {
        const int c = tid & 255, g = tid >> 8;
        const float* cb = contents + (b * TT + g * 64) * CC + c;
        float acc = 0.f;
        #pragma unroll 4
        for (int t = 0; t < 64; ++t) acc += w_in[g * 64 + t] * cb[t * CC];
        partc[g][c] = acc;
    }
    // ---- eff_p partials: p = tid&63, 8 t-groups of 16 ----
    {
        const int p = tid & 63, g = tid >> 6;
        const float* pb = pointers + (b * TT + g * 16) * PP + p;
        float acc = 0.f;
        #pragma unroll
        for (int t = 0; t < 16; ++t) acc += w_in[g * 16 + t] * pb[t * PP];
        part8[g][p] = acc;
    }
    __syncthreads();
    if (tid < CC) {
        float e = partc[0][tid] + partc[1][tid];
        ri[PP + tid] = e;
        eff_c_ws[bm * CC + tid] = e;
    } else if (tid < CC + PP) {
        const int p = tid - CC;
        float a = 0.f;
        #pragma unroll
        for (int g = 0; g < 8; ++g) a += part8[g][p];
        ri[p] = a;
    }
    __syncthreads();

    // ---- out_c = mem[m] @ eff_c: 16 lanes/row, 4 rows per wave-iter ----
    // lane's 16 eff_c values hoisted to registers (same for every row)
    {
        const int g = lane >> 4, j = lane & 15;
        float4 e_reg[4];
        #pragma unroll
        for (int k = 0; k < 4; ++k)
            e_reg[k] = *reinterpret_cast<const float4*>(&ri[PP + 4 * (j + 16 * k)]);
        const float4* mem4 = reinterpret_cast<const float4*>(memories) + m * (CC * CC / 4);
        #pragma unroll
        for (int i = 0; i < 8; ++i) {
            const int c = w * 32 + i * 4 + g;
            const float4* row4 = mem4 + c * 64;
            float s = 0.f;
            #pragma unroll
            for (int k = 0; k < 4; ++k) {
                float4 mv = row4[j + 16 * k];
                s += mv.x * e_reg[k].x + mv.y * e_reg[k].y
                   + mv.z * e_reg[k].z + mv.w * e_reg[k].w;
            }
            s += __shfl_xor(s, 1, 64);
            s += __shfl_xor(s, 2, 64);
            s += __shfl_xor(s, 4, 64);
            s += __shfl_xor(s, 8, 64);
            if (j == 0) outc_s[c] = s;
        }
    }

    // ---- MLP: h = relu(ri @ W1 + b1) ----
    {
        const float* w1 = W1 + m * 320 * 64;
        float acc = 0.f;
        const int i0 = w * 40;
        #pragma unroll 8
        for (int i = i0; i < i0 + 40; ++i) acc += ri[i] * w1[i * 64 + lane];
        __syncthreads();               // also covers outc_s completion
        part8[w][lane] = acc;
    }
    __syncthreads();
    if (tid < PP) {
        float s = b1[m * PP + tid];
        #pragma unroll
        for (int g = 0; g < 8; ++g) s += part8[g][tid];
        h[tid] = s > 0.f ? s : 0.f;
    }
    __syncthreads();
    {
        const float* w2 = W2 + m * 64 * 64;
        float acc = 0.f;
        const int i0 = w * 8;
        #pragma unroll
        for (int i = i0; i < i0 + 8; ++i) acc += h[i] * w2[i * 64 + lane];
        part8[w][lane] = acc;
    }
    __syncthreads();
    if (tid < PP) {
        float s = b2[m * PP + tid];
        #pragma unroll
        for (int g = 0; g < 8; ++g) s += part8[g][tid];
        outp_g[bm * PP + tid] = s > 0.f ? s : 0.f;
    }
    if (tid < CC) outc_g[bm * CC + tid] = outc_s[tid];
}

// ---- K3: fused route+stream, 32-row tiles. grid = 4096, b-MAJOR:
// gid = b*256 + m*8 + cs  -> 16 b-blocks sharing a (m,cs) tile are 256 apart
// (same XCD); prologue (nrm, wout, eoc) then NT-stream 32 KB.
__global__ __launch_bounds__(256) void K3_fused(
        const float* __restrict__ memories,
        const float* __restrict__ outp_g,
        const float* __restrict__ outc_g,
        const float* __restrict__ eff_c_ws,
        float* __restrict__ mems_out) {
    const int gid = blockIdx.x;
    const int b = gid >> 8;
    const int m = (gid >> 3) & 31, cs = gid & 7;
    const int bm = b * MM + m;
    const int tid = threadIdx.x;
    const int lane = tid & 63, w = tid >> 6;

    __shared__ float wout_s[MM];
    __shared__ float nrm_s[CC];
    __shared__ float eoc_s[32];
    __shared__ float red[4];

    // ---- nrm partial: ||eff_c||^2 ----
    const float ec = eff_c_ws[bm * CC + tid];
    {
        float v = ec * ec;
        #pragma unroll
        for (int off = 32; off; off >>= 1) v += __shfl_xor(v, off, 64);
        if (lane == 0) red[w] = v;
    }
    // ---- w_out row m: n = tid>>3, j = tid&7 (8 lanes per n) ----
    {
        const int n = tid >> 3, j = tid & 7;
        const float* opm = outp_g + bm * PP + j * 8;
        const float* opn = outp_g + (b * MM + n) * PP + j * 8;
        float s = 0.f;
        #pragma unroll
        for (int k = 0; k < 8; ++k) s += opm[k] * opn[k];
        s += __shfl_xor(s, 1, 64);
        s += __shfl_xor(s, 2, 64);
        s += __shfl_xor(s, 4, 64);
        if (j == 0) {
            float th = tanhf(s);
            wout_s[n] = th > 0.f ? th : 0.f;
        }
    }
    __syncthreads();
    nrm_s[tid] = ec / (red[0] + red[1] + red[2] + red[3] + 1e-42f);
    // ---- eoc slice (32 c's): c_local = tid>>3, k = tid&7, 4 n's per lane ----
    {
        const int c_local = tid >> 3, k = tid & 7;
        const int c = cs * 32 + c_local;
        const float* cb = outc_g + b * MM * CC + c;
        float s = 0.f;
        #pragma unroll
        for (int kk = 0; kk < 4; ++kk)
            s += wout_s[k * 4 + kk] * cb[(k * 4 + kk) * CC];
        s += __shfl_xor(s, 1, 64);
        s += __shfl_xor(s, 2, 64);
        s += __shfl_xor(s, 4, 64);
        if (k == 0) eoc_s[c_local] = s;
    }
    __syncthreads();

    // ---- stream 32 rows x 256 cols, NT stores ----
    const float4 nv = reinterpret_cast<const float4*>(nrm_s)[lane];
    const f32x4* mem4 = reinterpret_cast<const f32x4*>(memories) + (m * CC + cs * 32) * 64;
    f32x4* out4 = reinterpret_cast<f32x4*>(mems_out) + (bm * CC + cs * 32) * 64;

    #pragma unroll
    for (int it = 0; it < 8; ++it) {
        const int idx = it * 256 + tid;
        const float e = eoc_s[it * 4 + w];
        f32x4 mv = mem4[idx];
        f32x4 o;
        o.x = 0.5f * (mv.x + e * nv.x);
        o.y = 0.5f * (mv.y + e * nv.y);
        o.z = 0.5f * (mv.z + e * nv.z);
        o.w = 0.5f * (mv.w + e * nv.w);
        __builtin_nontemporal_store(o, &out4[idx]);
    }
}

extern "C" void kernel_launch(void* const* d_in, const int* in_sizes, int n_in,
                              void* d_out, int out_size, void* d_ws, size_t ws_size,
                              hipStream_t stream) {
    const float* pointers  = (const float*)d_in[0];
    const float* contents  = (const float*)d_in[1];
    const float* receivers = (const float*)d_in[2];
    const float* memories  = (const float*)d_in[3];
    const float* W1 = (const float*)d_in[4];
    const float* b1 = (const float*)d_in[5];
    const float* W2 = (const float*)d_in[6];
    const float* b2 = (const float*)d_in[7];

    float* out      = (float*)d_out;
    float* outp_g   = out;                       // 16*32*64
    float* outc_g   = out + 32768;               // 16*32*256
    float* mems_out = out + 32768 + 131072;      // 16*32*256*256

    float* eff_c = (float*)d_ws;       // 131072 floats

    hipLaunchKernelGGL(K1_front, dim3(BB * MM), dim3(512), 0, stream,
                       pointers, contents, receivers, memories, W1, b1, W2, b2,
                       eff_c, outp_g, outc_g);
    hipLaunchKernelGGL(K3_fused, dim3(BB * MM * 8), dim3(256), 0, stream,
                       memories, outp_g, outc_g, eff_c, mems_out);
}